// Round 3
// baseline (523.265 us; speedup 1.0000x reference)
//
#include <hip/hip_runtime.h>
#include <cstdint>
#include <cstddef>

typedef unsigned short u16;
typedef __attribute__((ext_vector_type(8))) short short8;
typedef __attribute__((ext_vector_type(4))) float v4f;

static constexpr size_t NN = (size_t)2048 * 2048;
#define N2 2048

__device__ __forceinline__ u16 f2b(float f) {
  union { float f; uint32_t u; } v; v.f = f;
  uint32_t r = v.u + 0x7fffu + ((v.u >> 16) & 1u);
  return (u16)(r >> 16);
}
__device__ __forceinline__ uint2 pack4(const float* f) {
  uint2 u;
  u.x = (uint32_t)f2b(f[0]) | ((uint32_t)f2b(f[1]) << 16);
  u.y = (uint32_t)f2b(f[2]) | ((uint32_t)f2b(f[3]) << 16);
  return u;
}
__device__ __forceinline__ uint4 pack8(const float* f) {
  uint4 u;
  u.x = (uint32_t)f2b(f[0]) | ((uint32_t)f2b(f[1]) << 16);
  u.y = (uint32_t)f2b(f[2]) | ((uint32_t)f2b(f[3]) << 16);
  u.z = (uint32_t)f2b(f[4]) | ((uint32_t)f2b(f[5]) << 16);
  u.w = (uint32_t)f2b(f[6]) | ((uint32_t)f2b(f[7]) << 16);
  return u;
}

// ---------------------------------------------------------------------------
// K0: one pass over fp32 A[5][N][N]: softmax-weighted sums -> abf (bf16,
// row-major), bbt = b^T, a1t = a1^T (bf16, via LDS-tiled transpose).
// 64x64 tile per block, 4 passes of 16 rows; each thread owns 4 columns.
// ---------------------------------------------------------------------------
__global__ __launch_bounds__(256) void conv_kernel(
    const float* __restrict__ A, const float* __restrict__ w1,
    const float* __restrict__ w2, const float* __restrict__ w3,
    u16* __restrict__ abf, u16* __restrict__ bbt, u16* __restrict__ a1t)
{
  __shared__ float lb[64][65];
  __shared__ float la[64][65];
  const int t = threadIdx.x;
  const int i0 = blockIdx.y * 64, j0 = blockIdx.x * 64;

  float s1[2][5], s2[2][5], s3[2][5];
  {
    const float* wsrc[3] = { w1, w2, w3 };
    float (*sdst[3])[5] = { s1, s2, s3 };
    for (int q = 0; q < 3; ++q)
      for (int c = 0; c < 2; ++c) {
        float v[5], m = -1e30f, sum = 0.f;
        for (int e = 0; e < 5; ++e) { v[e] = wsrc[q][c * 5 + e]; m = fmaxf(m, v[e]); }
        for (int e = 0; e < 5; ++e) { v[e] = expf(v[e] - m); sum += v[e]; }
        for (int e = 0; e < 5; ++e) sdst[q][c][e] = v[e] / sum;
      }
  }

  const int prow = t >> 4;        // 0..15
  const int c4 = (t & 15) * 4;    // col base within tile
  float cst[2][4][4];             // a1 stash [c][pass][u]

  for (int p = 0; p < 4; ++p) {
    const int row = p * 16 + prow;
    float fa[5][4];
    for (int e = 0; e < 5; ++e) {
      float4 v = *(const float4*)(A + (size_t)e * NN + (size_t)(i0 + row) * N2 + (j0 + c4));
      fa[e][0] = v.x; fa[e][1] = v.y; fa[e][2] = v.z; fa[e][3] = v.w;
    }
    for (int c = 0; c < 2; ++c) {
      float av[4] = {0,0,0,0}, bv[4] = {0,0,0,0}, cv[4] = {0,0,0,0};
      for (int e = 0; e < 5; ++e)
        #pragma unroll
        for (int u = 0; u < 4; ++u) {
          av[u] += s1[c][e] * fa[e][u];
          bv[u] += s2[c][e] * fa[e][u];
          cv[u] += s3[c][e] * fa[e][u];
        }
      *(uint2*)(abf + (size_t)c * NN + (size_t)(i0 + row) * N2 + (j0 + c4)) = pack4(av);
      float* ldst = (c == 0) ? &lb[row][c4] : &la[row][c4];
      #pragma unroll
      for (int u = 0; u < 4; ++u) ldst[u] = bv[u];
      #pragma unroll
      for (int u = 0; u < 4; ++u) cst[c][p][u] = cv[u];
    }
  }
  __syncthreads();
  {
    const int g8 = (t & 7) * 8;
    for (int q = 0; q < 2; ++q) {
      const int jrow = q * 32 + (t >> 3);
      float t0[8], t1[8];
      #pragma unroll
      for (int u = 0; u < 8; ++u) { t0[u] = lb[g8 + u][jrow]; t1[u] = la[g8 + u][jrow]; }
      *(uint4*)(bbt + 0 * NN + (size_t)(j0 + jrow) * N2 + (i0 + g8)) = pack8(t0);
      *(uint4*)(bbt + 1 * NN + (size_t)(j0 + jrow) * N2 + (i0 + g8)) = pack8(t1);
    }
  }
  __syncthreads();
  for (int p = 0; p < 4; ++p) {
    const int row = p * 16 + prow;
    #pragma unroll
    for (int u = 0; u < 4; ++u) { lb[row][c4 + u] = cst[0][p][u]; la[row][c4 + u] = cst[1][p][u]; }
  }
  __syncthreads();
  {
    const int g8 = (t & 7) * 8;
    for (int q = 0; q < 2; ++q) {
      const int jrow = q * 32 + (t >> 3);
      float t0[8], t1[8];
      #pragma unroll
      for (int u = 0; u < 8; ++u) { t0[u] = lb[g8 + u][jrow]; t1[u] = la[g8 + u][jrow]; }
      *(uint4*)(a1t + 0 * NN + (size_t)(j0 + jrow) * N2 + (i0 + g8)) = pack8(t0);
      *(uint4*)(a1t + 1 * NN + (size_t)(j0 + jrow) * N2 + (i0 + g8)) = pack8(t1);
    }
  }
}

// ---------------------------------------------------------------------------
// bf16 MFMA GEMM: C[c] = A[c] @ B[c], A [M][K] row-major bf16, Bt [N][K] bf16
// (B transposed, K-contiguous), C fp32. 128x128 tile, BK=64, 256 threads.
// VGPR-mediated staging; XOR granule swizzle (slot q of row r holds global
// k-granule q^(r&7); granule = 8 bf16 = 16 B) keeps ds_write_b128 and
// ds_read_b128 bank-balanced without padding.
// ---------------------------------------------------------------------------
__global__ __launch_bounds__(256) void gemm_kernel(
    const u16* __restrict__ Ain, const u16* __restrict__ Btin, float* __restrict__ C)
{
  const int c = blockIdx.z;
  const u16* Ac = Ain + (size_t)c * NN;
  const u16* Bc = Btin + (size_t)c * NN;
  float* Cc = C + (size_t)c * NN;
  const int m0 = blockIdx.y * 128, n0 = blockIdx.x * 128;
  const int t = threadIdx.x, w = t >> 6, lane = t & 63;
  const int quad = lane >> 4, r = lane & 15;
  const int wm = w >> 1, wn = w & 1;
  __shared__ u16 As[128 * 64];
  __shared__ u16 Bs[128 * 64];

  v4f zero4 = { 0.f, 0.f, 0.f, 0.f };
  v4f acc[4][4];
  #pragma unroll
  for (int i = 0; i < 4; ++i)
    #pragma unroll
    for (int j = 0; j < 4; ++j) acc[i][j] = zero4;

  const int srow = lane >> 3;            // row within this wave's 8-row chunk
  const int sgran = (lane & 7) ^ srow;   // swizzled global 8-elem k-granule

  for (int kt = 0; kt < 2048; kt += 64) {
    uint4 va[4], vb[4];
    #pragma unroll
    for (int i = 0; i < 4; ++i) {
      const int rowb = (i * 4 + w) * 8 + srow;
      va[i] = *(const uint4*)(Ac + (size_t)(m0 + rowb) * N2 + kt + sgran * 8);
      vb[i] = *(const uint4*)(Bc + (size_t)(n0 + rowb) * N2 + kt + sgran * 8);
    }
    __syncthreads();
    #pragma unroll
    for (int i = 0; i < 4; ++i) {
      *(uint4*)(As + (i * 4 + w) * 512 + lane * 8) = va[i];
      *(uint4*)(Bs + (i * 4 + w) * 512 + lane * 8) = vb[i];
    }
    __syncthreads();
    #pragma unroll
    for (int ks = 0; ks < 2; ++ks) {
      short8 af[4], bf[4];
      #pragma unroll
      for (int i = 0; i < 4; ++i) {
        const int row = wm * 64 + i * 16 + r;
        const int sl = ((ks * 4 + quad) ^ (r & 7)) * 8;
        af[i] = *(const short8*)(As + row * 64 + sl);
      }
      #pragma unroll
      for (int j = 0; j < 4; ++j) {
        const int row = wn * 64 + j * 16 + r;
        const int sl = ((ks * 4 + quad) ^ (r & 7)) * 8;
        bf[j] = *(const short8*)(Bs + row * 64 + sl);
      }
      #pragma unroll
      for (int i = 0; i < 4; ++i)
        #pragma unroll
        for (int j = 0; j < 4; ++j)
          acc[i][j] = __builtin_amdgcn_mfma_f32_16x16x32_bf16(af[i], bf[j], acc[i][j], 0, 0, 0);
    }
  }
  // Epilogue: C/D layout col=lane&15, row=quad*4+reg (m89-verified)
  #pragma unroll
  for (int i = 0; i < 4; ++i) {
    const int row = m0 + wm * 64 + i * 16 + quad * 4;
    #pragma unroll
    for (int j = 0; j < 4; ++j) {
      const int col = n0 + wn * 64 + j * 16 + r;
      #pragma unroll
      for (int g = 0; g < 4; ++g)
        Cc[(size_t)(row + g) * N2 + col] = acc[i][j][g];
    }
  }
}

// ---------------------------------------------------------------------------
// Column-sum partials of H (fp32 [2][N][N]): csp8[c][slab][q] (no atomics).
// ---------------------------------------------------------------------------
__global__ __launch_bounds__(256) void colsum_kernel(const float* __restrict__ H, float* __restrict__ csp8)
{
  const int c = blockIdx.z;
  const int q = blockIdx.x * 256 + threadIdx.x;
  const int p0 = blockIdx.y * 256;
  const float* Hc = H + (size_t)c * NN;
  float acc = 0.f;
  for (int p = 0; p < 256; ++p) acc += Hc[(size_t)(p0 + p) * N2 + q];
  csp8[((size_t)c * 8 + blockIdx.y) * N2 + q] = acc;
}

// colinv[c][q] = (deg==0) ? 0 : 1/(deg+eps), deg = colsum_q - H[q][q]
__global__ void colinv_kernel(const float* __restrict__ H, const float* __restrict__ csp8, float* __restrict__ ci)
{
  const int idx = blockIdx.x * 256 + threadIdx.x;  // [0, 4096)
  const int c = idx >> 11, q = idx & 2047;
  float cs = 0.f;
  #pragma unroll
  for (int s = 0; s < 8; ++s) cs += csp8[((size_t)c * 8 + s) * N2 + q];
  const float deg = cs - H[(size_t)c * NN + (size_t)q * N2 + q];
  ci[idx] = (deg == 0.f) ? 0.f : 1.f / (deg + 1e-8f);
}

// Hn[p][q] = bf16( p==q ? 0 : ci[q]*H[p][q] )
__global__ __launch_bounds__(256) void scale_kernel(const float* __restrict__ H, const float* __restrict__ ci, u16* __restrict__ Hn)
{
  const int idx = blockIdx.x * 256 + threadIdx.x;
  const int q0 = (idx & 255) * 8;
  const int p = (idx >> 8) & 2047;
  const int c = idx >> 19;
  const float* src = H + (size_t)c * NN + (size_t)p * N2 + q0;
  const float* cv = ci + c * N2 + q0;
  float f[8];
  #pragma unroll
  for (int u = 0; u < 8; ++u) {
    float v = src[u] * cv[u];
    f[u] = (q0 + u == p) ? 0.f : v;
  }
  *(uint4*)(Hn + (size_t)c * NN + (size_t)p * N2 + q0) = pack8(f);
}

// Xw = X @ gcn_weight (all fp32)
__global__ __launch_bounds__(256) void xw_kernel(const float* __restrict__ X, const float* __restrict__ W, float* __restrict__ Xw)
{
  const int t = threadIdx.x;
  const int k = t & 63;
  const int n = blockIdx.x * 4 + (t >> 6);
  float acc = 0.f;
  for (int m = 0; m < 256; ++m)
    acc += X[n * 256 + m] * W[m * 64 + k];
  Xw[n * 64 + k] = acc;
}

// ---------------------------------------------------------------------------
// One streaming pass over H2: partial T = H2^T @ Xw and partial colsums,
// split over 8 j-slabs. grid (32 i-tiles, 8 slabs, 2 c), 256 threads.
// ---------------------------------------------------------------------------
__global__ __launch_bounds__(256) void tpart_kernel(const float* __restrict__ H2, const float* __restrict__ Xw,
                                                    float* __restrict__ Tp, float* __restrict__ csp)
{
  const int c = blockIdx.z, slab = blockIdx.y;
  const int i0 = blockIdx.x * 64;
  const int t = threadIdx.x, ti = t & 15, tk = t >> 4;
  __shared__ __attribute__((aligned(16))) float H2s[8][64];
  __shared__ __attribute__((aligned(16))) float Xws[8][64];
  const float* H2c = H2 + (size_t)c * NN;
  float acc[4][4] = {};
  float cs = 0.f;
  const int jj0 = t >> 6, col = t & 63;

  for (int s = 0; s < 32; ++s) {
    const int jb = slab * 256 + s * 8;
    __syncthreads();
    H2s[jj0][col]     = H2c[(size_t)(jb + jj0) * N2 + i0 + col];
    H2s[jj0 + 4][col] = H2c[(size_t)(jb + jj0 + 4) * N2 + i0 + col];
    Xws[jj0][col]     = Xw[(jb + jj0) * 64 + col];
    Xws[jj0 + 4][col] = Xw[(jb + jj0 + 4) * 64 + col];
    __syncthreads();
    if (t < 64) {
      #pragma unroll
      for (int jj = 0; jj < 8; ++jj) cs += H2s[jj][t];
    }
    #pragma unroll
    for (int jj = 0; jj < 8; ++jj) {
      const float4 h = *(const float4*)&H2s[jj][ti * 4];
      const float4 x = *(const float4*)&Xws[jj][tk * 4];
      const float ha[4] = { h.x, h.y, h.z, h.w };
      const float xa[4] = { x.x, x.y, x.z, x.w };
      #pragma unroll
      for (int a = 0; a < 4; ++a)
        #pragma unroll
        for (int b = 0; b < 4; ++b)
          acc[a][b] += ha[a] * xa[b];
    }
  }
  const size_t rbase = (size_t)(slab * 2 + c) * 2048 + i0;
  #pragma unroll
  for (int a = 0; a < 4; ++a) {
    float4 o; o.x = acc[a][0]; o.y = acc[a][1]; o.z = acc[a][2]; o.w = acc[a][3];
    *(float4*)&Tp[(rbase + ti * 4 + a) * 64 + tk * 4] = o;
  }
  if (t < 64) csp[rbase + t] = cs;
}

// out[i][c*64+k] = relu( dinv * (T - H2[i][i]*Xw[i][k] + Xw[i][k]) ), fp32
__global__ void epilogue_kernel(const float* __restrict__ Tp, const float* __restrict__ csp,
                                const float* __restrict__ H2, const float* __restrict__ Xw,
                                float* __restrict__ out)
{
  const int idx = blockIdx.x * 256 + threadIdx.x;
  const int k = idx & 63;
  const int c = (idx >> 6) & 1;
  const int i = idx >> 7;
  float T = 0.f, cs = 0.f;
  #pragma unroll
  for (int s = 0; s < 8; ++s) {
    T  += Tp[((size_t)(s * 2 + c) * 2048 + i) * 64 + k];
    cs += csp[(s * 2 + c) * 2048 + i];
  }
  const float hd = H2[(size_t)c * NN + (size_t)i * N2 + i];
  const float xw = Xw[i * 64 + k];
  const float deg = cs - hd + 1.0f;  // add=True: diag set to 1 contributes +1
  const float dinv = (deg == 0.f) ? 0.f : 1.f / (deg + 1e-8f);
  float v = dinv * (T - hd * xw + xw);
  v = v > 0.f ? v : 0.f;
  out[(size_t)i * 128 + c * 64 + k] = v;
}

// ---------------------------------------------------------------------------
// Workspace layout (bytes), peak ~96.7 MiB, all reads preceded by writes
// (no memset / no atomics anywhere):
//   abf  @ 0          (16.78 MB bf16)  -- dead after GEMM1
//   bbt  @ 16777216   (16.78 MB bf16)  -- dead after GEMM1
//   a1t  @ 33554432   (16.78 MB bf16)
//   H    @ 50331648   (33.55 MB fp32)  -- dead after scale_kernel
//   Hn   @ 83886080   (16.78 MB bf16)
//   Xw   @ 100663296  (0.52 MB fp32)
//   csp8 @ 101187584  (128 KB)
//   ci1  @ 101318656  (16 KB)          -- end 101335040
//   H2   @ 0          (33.55 MB fp32, over abf+bbt)
//   Tp   @ 50331648   (8.39 MB fp32, over H)
//   csp  @ 58720256   (128 KB, over H)
// ---------------------------------------------------------------------------
extern "C" void kernel_launch(void* const* d_in, const int* in_sizes, int n_in,
                              void* d_out, int out_size, void* d_ws, size_t ws_size,
                              hipStream_t stream) {
  const float* A  = (const float*)d_in[0];
  const float* X  = (const float*)d_in[1];
  const float* w1 = (const float*)d_in[2];
  const float* w2 = (const float*)d_in[3];
  const float* w3 = (const float*)d_in[4];
  const float* W  = (const float*)d_in[5];
  float* out = (float*)d_out;
  char* ws = (char*)d_ws;

  u16*   abf  = (u16*)(ws + 0);
  u16*   bbt  = (u16*)(ws + 16777216);
  u16*   a1t  = (u16*)(ws + 33554432);
  float* H    = (float*)(ws + 50331648);
  u16*   Hn   = (u16*)(ws + 83886080);
  float* Xw   = (float*)(ws + 100663296);
  float* csp8 = (float*)(ws + 101187584);
  float* ci1  = (float*)(ws + 101318656);
  float* H2   = (float*)(ws + 0);
  float* Tp   = (float*)(ws + 50331648);
  float* csp  = (float*)(ws + 58720256);

  conv_kernel<<<dim3(32, 32), 256, 0, stream>>>(A, w1, w2, w3, abf, bbt, a1t);
  xw_kernel<<<512, 256, 0, stream>>>(X, W, Xw);
  gemm_kernel<<<dim3(16, 16, 2), 256, 0, stream>>>(abf, bbt, H);
  colsum_kernel<<<dim3(8, 8, 2), 256, 0, stream>>>(H, csp8);
  colinv_kernel<<<16, 256, 0, stream>>>(H, csp8, ci1);
  scale_kernel<<<4096, 256, 0, stream>>>(H, ci1, Hn);
  gemm_kernel<<<dim3(16, 16, 2), 256, 0, stream>>>(Hn, a1t, H2);
  tpart_kernel<<<dim3(32, 8, 2), 256, 0, stream>>>(H2, Xw, Tp, csp);
  epilogue_kernel<<<1024, 256, 0, stream>>>(Tp, csp, H2, Xw, out);
}

// Round 4
// 297.547 us; speedup vs baseline: 1.7586x; 1.7586x over previous
//
#include <hip/hip_runtime.h>
#include <cstdint>
#include <cstddef>

typedef unsigned short u16;
typedef __attribute__((ext_vector_type(8))) short short8;
typedef __attribute__((ext_vector_type(4))) float v4f;

static constexpr size_t NN = (size_t)2048 * 2048;
#define N2 2048

typedef __attribute__((address_space(1))) const unsigned int guint;
typedef __attribute__((address_space(3))) unsigned int luint;

__device__ __forceinline__ u16 f2b(float f) {
  union { float f; uint32_t u; } v; v.f = f;
  uint32_t r = v.u + 0x7fffu + ((v.u >> 16) & 1u);
  return (u16)(r >> 16);
}
__device__ __forceinline__ uint2 pack4(const float* f) {
  uint2 u;
  u.x = (uint32_t)f2b(f[0]) | ((uint32_t)f2b(f[1]) << 16);
  u.y = (uint32_t)f2b(f[2]) | ((uint32_t)f2b(f[3]) << 16);
  return u;
}
__device__ __forceinline__ uint4 pack8(const float* f) {
  uint4 u;
  u.x = (uint32_t)f2b(f[0]) | ((uint32_t)f2b(f[1]) << 16);
  u.y = (uint32_t)f2b(f[2]) | ((uint32_t)f2b(f[3]) << 16);
  u.z = (uint32_t)f2b(f[4]) | ((uint32_t)f2b(f[5]) << 16);
  u.w = (uint32_t)f2b(f[6]) | ((uint32_t)f2b(f[7]) << 16);
  return u;
}

// ---------------------------------------------------------------------------
// K0: one pass over fp32 A[5][N][N]: softmax-weighted sums -> abf (bf16,
// row-major), bbt = b^T, a1t = a1^T (bf16, via LDS-tiled transpose).
// ---------------------------------------------------------------------------
__global__ __launch_bounds__(256) void conv_kernel(
    const float* __restrict__ A, const float* __restrict__ w1,
    const float* __restrict__ w2, const float* __restrict__ w3,
    u16* __restrict__ abf, u16* __restrict__ bbt, u16* __restrict__ a1t)
{
  __shared__ float lb[64][65];
  __shared__ float la[64][65];
  const int t = threadIdx.x;
  const int i0 = blockIdx.y * 64, j0 = blockIdx.x * 64;

  float s1[2][5], s2[2][5], s3[2][5];
  {
    const float* wsrc[3] = { w1, w2, w3 };
    float (*sdst[3])[5] = { s1, s2, s3 };
    for (int q = 0; q < 3; ++q)
      for (int c = 0; c < 2; ++c) {
        float v[5], m = -1e30f, sum = 0.f;
        for (int e = 0; e < 5; ++e) { v[e] = wsrc[q][c * 5 + e]; m = fmaxf(m, v[e]); }
        for (int e = 0; e < 5; ++e) { v[e] = expf(v[e] - m); sum += v[e]; }
        for (int e = 0; e < 5; ++e) sdst[q][c][e] = v[e] / sum;
      }
  }

  const int prow = t >> 4;        // 0..15
  const int c4 = (t & 15) * 4;    // col base within tile
  float cst[2][4][4];             // a1 stash [c][pass][u]

  for (int p = 0; p < 4; ++p) {
    const int row = p * 16 + prow;
    float fa[5][4];
    for (int e = 0; e < 5; ++e) {
      float4 v = *(const float4*)(A + (size_t)e * NN + (size_t)(i0 + row) * N2 + (j0 + c4));
      fa[e][0] = v.x; fa[e][1] = v.y; fa[e][2] = v.z; fa[e][3] = v.w;
    }
    for (int c = 0; c < 2; ++c) {
      float av[4] = {0,0,0,0}, bv[4] = {0,0,0,0}, cv[4] = {0,0,0,0};
      for (int e = 0; e < 5; ++e)
        #pragma unroll
        for (int u = 0; u < 4; ++u) {
          av[u] += s1[c][e] * fa[e][u];
          bv[u] += s2[c][e] * fa[e][u];
          cv[u] += s3[c][e] * fa[e][u];
        }
      *(uint2*)(abf + (size_t)c * NN + (size_t)(i0 + row) * N2 + (j0 + c4)) = pack4(av);
      float* ldst = (c == 0) ? &lb[row][c4] : &la[row][c4];
      #pragma unroll
      for (int u = 0; u < 4; ++u) ldst[u] = bv[u];
      #pragma unroll
      for (int u = 0; u < 4; ++u) cst[c][p][u] = cv[u];
    }
  }
  __syncthreads();
  {
    const int g8 = (t & 7) * 8;
    for (int q = 0; q < 2; ++q) {
      const int jrow = q * 32 + (t >> 3);
      float t0[8], t1[8];
      #pragma unroll
      for (int u = 0; u < 8; ++u) { t0[u] = lb[g8 + u][jrow]; t1[u] = la[g8 + u][jrow]; }
      *(uint4*)(bbt + 0 * NN + (size_t)(j0 + jrow) * N2 + (i0 + g8)) = pack8(t0);
      *(uint4*)(bbt + 1 * NN + (size_t)(j0 + jrow) * N2 + (i0 + g8)) = pack8(t1);
    }
  }
  __syncthreads();
  for (int p = 0; p < 4; ++p) {
    const int row = p * 16 + prow;
    #pragma unroll
    for (int u = 0; u < 4; ++u) { lb[row][c4 + u] = cst[0][p][u]; la[row][c4 + u] = cst[1][p][u]; }
  }
  __syncthreads();
  {
    const int g8 = (t & 7) * 8;
    for (int q = 0; q < 2; ++q) {
      const int jrow = q * 32 + (t >> 3);
      float t0[8], t1[8];
      #pragma unroll
      for (int u = 0; u < 8; ++u) { t0[u] = lb[g8 + u][jrow]; t1[u] = la[g8 + u][jrow]; }
      *(uint4*)(a1t + 0 * NN + (size_t)(j0 + jrow) * N2 + (i0 + g8)) = pack8(t0);
      *(uint4*)(a1t + 1 * NN + (size_t)(j0 + jrow) * N2 + (i0 + g8)) = pack8(t1);
    }
  }
}

// ---------------------------------------------------------------------------
// bf16 MFMA GEMM: C[c] = A[c] @ B[c], A [M][K] row-major bf16, Bt [N][K] bf16
// (K-contiguous), C fp32. 128x64 tile (M x N), BK=64, 256 threads = 4 waves,
// each wave owns 32 rows x 64 cols. global_load_lds width-16 staging with
// XOR granule swizzle (slot q of row r holds k-granule q^(r&7), granule =
// 8 bf16 = 16 B) -> conflict-free ds_read_b128 fragment loads.
// Grid 32x16x2 = 1024 blocks; LDS 24 KB, 5 blocks/CU resident.
// ---------------------------------------------------------------------------
__global__ __launch_bounds__(256, 5) void gemm_kernel(
    const u16* __restrict__ Ain, const u16* __restrict__ Btin, float* __restrict__ C)
{
  const int c = blockIdx.z;
  const u16* Ac = Ain + (size_t)c * NN;
  const u16* Bc = Btin + (size_t)c * NN;
  float* Cc = C + (size_t)c * NN;
  const int m0 = blockIdx.y * 128, n0 = blockIdx.x * 64;
  const int t = threadIdx.x, w = t >> 6, lane = t & 63;
  const int quad = lane >> 4, r = lane & 15;
  __shared__ u16 As[128 * 64];
  __shared__ u16 Bs[64 * 64];

  v4f zero4 = { 0.f, 0.f, 0.f, 0.f };
  v4f acc[2][4];
  #pragma unroll
  for (int i = 0; i < 2; ++i)
    #pragma unroll
    for (int j = 0; j < 4; ++j) acc[i][j] = zero4;

  const int srow = lane >> 3;            // row within an 8-row chunk
  const int sgran = (lane & 7) ^ srow;   // swizzled k-granule

  for (int kt = 0; kt < 2048; kt += 64) {
    __syncthreads();
    #pragma unroll
    for (int i = 0; i < 4; ++i) {
      const int chunk = i * 4 + w;
      const u16* ga = Ac + (size_t)(m0 + chunk * 8 + srow) * N2 + kt + sgran * 8;
      __builtin_amdgcn_global_load_lds((guint*)ga, (luint*)(As + chunk * 512), 16, 0, 0);
    }
    #pragma unroll
    for (int i = 0; i < 2; ++i) {
      const int chunk = i * 4 + w;
      const u16* gb = Bc + (size_t)(n0 + chunk * 8 + srow) * N2 + kt + sgran * 8;
      __builtin_amdgcn_global_load_lds((guint*)gb, (luint*)(Bs + chunk * 512), 16, 0, 0);
    }
    __syncthreads();
    #pragma unroll
    for (int ks = 0; ks < 2; ++ks) {
      const int sl = ((ks * 4 + quad) ^ (r & 7)) * 8;
      short8 af[2], bf[4];
      #pragma unroll
      for (int i = 0; i < 2; ++i)
        af[i] = *(const short8*)(As + (w * 32 + i * 16 + r) * 64 + sl);
      #pragma unroll
      for (int j = 0; j < 4; ++j)
        bf[j] = *(const short8*)(Bs + (j * 16 + r) * 64 + sl);
      #pragma unroll
      for (int i = 0; i < 2; ++i)
        #pragma unroll
        for (int j = 0; j < 4; ++j)
          acc[i][j] = __builtin_amdgcn_mfma_f32_16x16x32_bf16(af[i], bf[j], acc[i][j], 0, 0, 0);
    }
  }
  // Epilogue: C/D layout col=lane&15, row=quad*4+reg (m89-verified)
  #pragma unroll
  for (int i = 0; i < 2; ++i) {
    const int row = m0 + w * 32 + i * 16 + quad * 4;
    #pragma unroll
    for (int j = 0; j < 4; ++j) {
      const int col = n0 + j * 16 + r;
      #pragma unroll
      for (int g = 0; g < 4; ++g)
        Cc[(size_t)(row + g) * N2 + col] = acc[i][j][g];
    }
  }
}

// ---------------------------------------------------------------------------
// Column-sum partials of H (fp32 [2][N][N]): csp32[c][slab32][q], 64 rows/blk.
// ---------------------------------------------------------------------------
__global__ __launch_bounds__(256) void colsum_kernel(const float* __restrict__ H, float* __restrict__ csp32)
{
  const int c = blockIdx.z;
  const int q = blockIdx.x * 256 + threadIdx.x;
  const int p0 = blockIdx.y * 64;
  const float* Hc = H + (size_t)c * NN;
  float acc = 0.f;
  for (int p = 0; p < 64; ++p) acc += Hc[(size_t)(p0 + p) * N2 + q];
  csp32[((size_t)c * 32 + blockIdx.y) * N2 + q] = acc;
}

// colinv[c][q] = (deg==0) ? 0 : 1/(deg+eps), deg = colsum_q - H[q][q]
__global__ void colinv_kernel(const float* __restrict__ H, const float* __restrict__ csp32, float* __restrict__ ci)
{
  const int idx = blockIdx.x * 256 + threadIdx.x;  // [0, 4096)
  const int c = idx >> 11, q = idx & 2047;
  float cs = 0.f;
  #pragma unroll
  for (int s = 0; s < 32; ++s) cs += csp32[((size_t)c * 32 + s) * N2 + q];
  const float deg = cs - H[(size_t)c * NN + (size_t)q * N2 + q];
  ci[idx] = (deg == 0.f) ? 0.f : 1.f / (deg + 1e-8f);
}

// Hn[p][q] = bf16( p==q ? 0 : ci[q]*H[p][q] )
__global__ __launch_bounds__(256) void scale_kernel(const float* __restrict__ H, const float* __restrict__ ci, u16* __restrict__ Hn)
{
  const int idx = blockIdx.x * 256 + threadIdx.x;
  const int q0 = (idx & 255) * 8;
  const int p = (idx >> 8) & 2047;
  const int c = idx >> 19;
  const float* src = H + (size_t)c * NN + (size_t)p * N2 + q0;
  const float* cv = ci + c * N2 + q0;
  float f[8];
  #pragma unroll
  for (int u = 0; u < 8; ++u) {
    float v = src[u] * cv[u];
    f[u] = (q0 + u == p) ? 0.f : v;
  }
  *(uint4*)(Hn + (size_t)c * NN + (size_t)p * N2 + q0) = pack8(f);
}

// Xw = X @ gcn_weight (all fp32)
__global__ __launch_bounds__(256) void xw_kernel(const float* __restrict__ X, const float* __restrict__ W, float* __restrict__ Xw)
{
  const int t = threadIdx.x;
  const int k = t & 63;
  const int n = blockIdx.x * 4 + (t >> 6);
  float acc = 0.f;
  for (int m = 0; m < 256; ++m)
    acc += X[n * 256 + m] * W[m * 64 + k];
  Xw[n * 64 + k] = acc;
}

// ---------------------------------------------------------------------------
// T-partials: Tp[slab][i][k] = sum_{j in slab} H2[j][i]*Xw[j][k] plus slab
// column-sums of H2. Grid (32 i-tiles, 16 slabs of 128 rows, 2 c), 256 thr.
// 16 rows staged per step -> 16 barriers/block (was 64).
// ---------------------------------------------------------------------------
__global__ __launch_bounds__(256) void tpart_kernel(const float* __restrict__ H2, const float* __restrict__ Xw,
                                                    float* __restrict__ Tp, float* __restrict__ csp)
{
  const int c = blockIdx.z, slab = blockIdx.y;
  const int i0 = blockIdx.x * 64;
  const int t = threadIdx.x, ti = t & 15, tk = t >> 4;
  const int col = t & 63, rgrp = t >> 6;
  __shared__ __attribute__((aligned(16))) float H2s[16][64];
  __shared__ __attribute__((aligned(16))) float Xws[16][64];
  __shared__ float csred[4][64];
  const float* H2c = H2 + (size_t)c * NN;
  float acc[4][4] = {};
  float cs_priv = 0.f;

  for (int s = 0; s < 8; ++s) {
    const int jb = slab * 128 + s * 16;
    __syncthreads();
    #pragma unroll
    for (int rr = 0; rr < 4; ++rr) {
      const int jj = rr * 4 + rgrp;
      const float hv = H2c[(size_t)(jb + jj) * N2 + i0 + col];
      H2s[jj][col] = hv;
      cs_priv += hv;
      Xws[jj][col] = Xw[(jb + jj) * 64 + col];
    }
    __syncthreads();
    #pragma unroll
    for (int jj = 0; jj < 16; ++jj) {
      const float4 h = *(const float4*)&H2s[jj][ti * 4];
      const float4 x = *(const float4*)&Xws[jj][tk * 4];
      const float ha[4] = { h.x, h.y, h.z, h.w };
      const float xa[4] = { x.x, x.y, x.z, x.w };
      #pragma unroll
      for (int a = 0; a < 4; ++a)
        #pragma unroll
        for (int b = 0; b < 4; ++b)
          acc[a][b] += ha[a] * xa[b];
    }
  }
  const size_t rbase = (size_t)(slab * 2 + c) * 2048 + i0;
  #pragma unroll
  for (int a = 0; a < 4; ++a) {
    float4 o; o.x = acc[a][0]; o.y = acc[a][1]; o.z = acc[a][2]; o.w = acc[a][3];
    *(float4*)&Tp[(rbase + ti * 4 + a) * 64 + tk * 4] = o;
  }
  __syncthreads();
  csred[rgrp][col] = cs_priv;
  __syncthreads();
  if (t < 64) csp[rbase + t] = csred[0][t] + csred[1][t] + csred[2][t] + csred[3][t];
}

// out[i][c*64+k] = relu( dinv * (T - H2[i][i]*Xw[i][k] + Xw[i][k]) ), fp32
__global__ void epilogue_kernel(const float* __restrict__ Tp, const float* __restrict__ csp,
                                const float* __restrict__ H2, const float* __restrict__ Xw,
                                float* __restrict__ out)
{
  const int idx = blockIdx.x * 256 + threadIdx.x;
  const int k = idx & 63;
  const int c = (idx >> 6) & 1;
  const int i = idx >> 7;
  float T = 0.f, cs = 0.f;
  #pragma unroll
  for (int s = 0; s < 16; ++s) {
    T  += Tp[((size_t)(s * 2 + c) * 2048 + i) * 64 + k];
    cs += csp[(s * 2 + c) * 2048 + i];
  }
  const float hd = H2[(size_t)c * NN + (size_t)i * N2 + i];
  const float xw = Xw[i * 64 + k];
  const float deg = cs - hd + 1.0f;  // add=True: diag set to 1 contributes +1
  const float dinv = (deg == 0.f) ? 0.f : 1.f / (deg + 1e-8f);
  float v = dinv * (T - hd * xw + xw);
  v = v > 0.f ? v : 0.f;
  out[(size_t)i * 128 + c * 64 + k] = v;
}

// ---------------------------------------------------------------------------
// Workspace layout (bytes), peak ~101.7 MB, all reads preceded by writes:
//   abf   @ 0          (16.78 MB bf16)  -- dead after GEMM1
//   bbt   @ 16777216   (16.78 MB bf16)  -- dead after GEMM1
//   a1t   @ 33554432   (16.78 MB bf16)
//   H     @ 50331648   (33.55 MB fp32)  -- dead after scale_kernel
//   Hn    @ 83886080   (16.78 MB bf16)
//   Xw    @ 100663296  (0.52 MB fp32)
//   csp32 @ 101187584  (512 KB)
//   ci1   @ 101711872  (16 KB)          -- end 101728256
//   H2    @ 0          (33.55 MB fp32, over abf+bbt)
//   Tp    @ 50331648   (16.78 MB fp32, over H)
//   csp   @ 67108864   (256 KB, over H)
// ---------------------------------------------------------------------------
extern "C" void kernel_launch(void* const* d_in, const int* in_sizes, int n_in,
                              void* d_out, int out_size, void* d_ws, size_t ws_size,
                              hipStream_t stream) {
  const float* A  = (const float*)d_in[0];
  const float* X  = (const float*)d_in[1];
  const float* w1 = (const float*)d_in[2];
  const float* w2 = (const float*)d_in[3];
  const float* w3 = (const float*)d_in[4];
  const float* W  = (const float*)d_in[5];
  float* out = (float*)d_out;
  char* ws = (char*)d_ws;

  u16*   abf   = (u16*)(ws + 0);
  u16*   bbt   = (u16*)(ws + 16777216);
  u16*   a1t   = (u16*)(ws + 33554432);
  float* H     = (float*)(ws + 50331648);
  u16*   Hn    = (u16*)(ws + 83886080);
  float* Xw    = (float*)(ws + 100663296);
  float* csp32 = (float*)(ws + 101187584);
  float* ci1   = (float*)(ws + 101711872);
  float* H2    = (float*)(ws + 0);
  float* Tp    = (float*)(ws + 50331648);
  float* csp   = (float*)(ws + 67108864);

  conv_kernel<<<dim3(32, 32), 256, 0, stream>>>(A, w1, w2, w3, abf, bbt, a1t);
  xw_kernel<<<512, 256, 0, stream>>>(X, W, Xw);
  gemm_kernel<<<dim3(32, 16, 2), 256, 0, stream>>>(abf, bbt, H);
  colsum_kernel<<<dim3(8, 32, 2), 256, 0, stream>>>(H, csp32);
  colinv_kernel<<<16, 256, 0, stream>>>(H, csp32, ci1);
  scale_kernel<<<4096, 256, 0, stream>>>(H, ci1, Hn);
  gemm_kernel<<<dim3(32, 16, 2), 256, 0, stream>>>(Hn, a1t, H2);
  tpart_kernel<<<dim3(32, 16, 2), 256, 0, stream>>>(H2, Xw, Tp, csp);
  epilogue_kernel<<<1024, 256, 0, stream>>>(Tp, csp, H2, Xw, out);
}